// Round 1
// baseline (943.279 us; speedup 1.0000x reference)
//
#include <hip/hip_runtime.h>
#include <math.h>

#define N_RAYS 8192
#define T_SAMPLES 64
#define HID 128
#define S_CHUNK 8
#define RAYS_PER_BLOCK 4
#define THREADS (RAYS_PER_BLOCK * 128)
#define FAR_T 10.0f
#define BOOSTER 1.0f

__global__ __launch_bounds__(THREADS, 1)
void RadianceRenderer_kernel(const float* __restrict__ rays_o, const float* __restrict__ rays_d,
                             const float* __restrict__ aabb,
                             const float* __restrict__ W1, const float* __restrict__ b1,
                             const float* __restrict__ W2, const float* __restrict__ b2,
                             const float* __restrict__ Wd, const float* __restrict__ bd,
                             const float* __restrict__ Wf, const float* __restrict__ bf,
                             const float* __restrict__ Wc1, const float* __restrict__ bc1,
                             const float* __restrict__ Wc2, const float* __restrict__ bc2,
                             float* __restrict__ out)
{
    // ---- LDS: weights (staged once) + per-ray sample buffers (~130 KB) ----
    __shared__ float W1s[3][HID];          // 1.5 KB
    __shared__ float b1s[HID];
    __shared__ float W2s[HID][HID];        // 64 KB
    __shared__ float b2s[HID];
    __shared__ float Wds[HID];
    __shared__ float Wfs[HID][16];         // 8 KB
    __shared__ float bfs[16];
    __shared__ float Wc1s[32][HID];        // 16 KB
    __shared__ float bc1s[HID];
    __shared__ float Wc2s[HID][3];
    __shared__ float bc2s[3];
    __shared__ float bds;
    __shared__ float h1s[RAYS_PER_BLOCK][HID][S_CHUNK];   // 16 KB (reused as hc)
    __shared__ float h2s[RAYS_PER_BLOCK][HID][S_CHUNK];   // 16 KB
    __shared__ float cats[RAYS_PER_BLOCK][S_CHUNK][32];   // 4 KB
    __shared__ float ynms[RAYS_PER_BLOCK][16];
    __shared__ float sigs[RAYS_PER_BLOCK][S_CHUNK];
    __shared__ float cols[RAYS_PER_BLOCK][S_CHUNK][3];

    const int tid = threadIdx.x;

    // ---- stage weights into LDS (coalesced float4) ----
    for (int i = tid; i < 4096; i += THREADS) ((float4*)W2s)[i]  = ((const float4*)W2)[i];
    for (int i = tid; i < 1024; i += THREADS) ((float4*)Wc1s)[i] = ((const float4*)Wc1)[i];
    for (int i = tid; i < 512;  i += THREADS) ((float4*)Wfs)[i]  = ((const float4*)Wf)[i];
    for (int i = tid; i < 96;   i += THREADS) ((float4*)W1s)[i]  = ((const float4*)W1)[i];
    for (int i = tid; i < 96;   i += THREADS) ((float4*)Wc2s)[i] = ((const float4*)Wc2)[i];
    for (int i = tid; i < 32;   i += THREADS) ((float4*)b1s)[i]  = ((const float4*)b1)[i];
    for (int i = tid; i < 32;   i += THREADS) ((float4*)b2s)[i]  = ((const float4*)b2)[i];
    for (int i = tid; i < 32;   i += THREADS) ((float4*)Wds)[i]  = ((const float4*)Wd)[i];
    for (int i = tid; i < 32;   i += THREADS) ((float4*)bc1s)[i] = ((const float4*)bc1)[i];
    for (int i = tid; i < 4;    i += THREADS) ((float4*)bfs)[i]  = ((const float4*)bf)[i];
    if (tid == 0) { bds = bd[0]; bc2s[0] = bc2[0]; bc2s[1] = bc2[1]; bc2s[2] = bc2[2]; }

    const float a0x = aabb[0], a0y = aabb[1], a0z = aabb[2];
    const float a1x = aabb[3], a1y = aabb[4], a1z = aabb[5];
    const float scx = 2.0f / (a1x - a0x), scy = 2.0f / (a1y - a0y), scz = 2.0f / (a1z - a0z);

    const int sg = tid >> 7;        // sub-group = ray slot (0..3)
    const int j  = tid & 127;       // hidden-unit lane
    const int sf = j >> 4;          // sample index for reduction tasks (0..7)
    const int jf = j & 15;          // k-slice / feature index (0..15)

    __syncthreads();

    for (int g = blockIdx.x; g < N_RAYS / RAYS_PER_BLOCK; g += gridDim.x) {
        const int ray = g * RAYS_PER_BLOCK + sg;

        const float ox = rays_o[ray*3+0], oy = rays_o[ray*3+1], oz = rays_o[ray*3+2];
        const float dx = rays_d[ray*3+0], dy = rays_d[ray*3+1], dz = rays_d[ray*3+2];

        // slab test
        const float ivx = 1.0f/dx, ivy = 1.0f/dy, ivz = 1.0f/dz;
        float t1x = (a0x-ox)*ivx, t2x = (a1x-ox)*ivx;
        float t1y = (a0y-oy)*ivy, t2y = (a1y-oy)*ivy;
        float t1z = (a0z-oz)*ivz, t2z = (a1z-oz)*ivz;
        float tn0 = fmaxf(fmaxf(fminf(t1x,t2x), fminf(t1y,t2y)), fminf(t1z,t2z));
        tn0 = fmaxf(tn0, 0.0f);
        float tf0 = fminf(fminf(fmaxf(t1x,t2x), fmaxf(t1y,t2y)), fmaxf(t1z,t2z));
        tf0 = fminf(tf0, FAR_T);
        const bool act = tn0 < tf0;
        const float tn = act ? tn0 : 0.0f;
        const float tf = act ? tf0 : 1.0f;
        const float tstep = (tf - tn) * (1.0f / T_SAMPLES);

        const float dnorm = sqrtf(dx*dx + dy*dy + dz*dz);
        const float nxd = dx/dnorm, nyd = dy/dnorm, nzd = dz/dnorm;

        if (j < 16) {
            const float x = nxd, y = nyd, z = nzd;
            const float x2 = x*x, y2 = y*y, z2 = z*z;
            float v;
            switch (j) {
                case 0:  v = 0.282094791773878f; break;
                case 1:  v = -0.488602511902920f * y; break;
                case 2:  v = 0.488602511902920f * z; break;
                case 3:  v = -0.488602511902920f * x; break;
                case 4:  v = 1.092548430592079f * x * y; break;
                case 5:  v = -1.092548430592079f * y * z; break;
                case 6:  v = 0.315391565252520f * (3.0f*z2 - 1.0f); break;
                case 7:  v = -1.092548430592079f * x * z; break;
                case 8:  v = 0.546274215296040f * (x2 - y2); break;
                case 9:  v = -0.590043589926644f * y * (3.0f*x2 - y2); break;
                case 10: v = 2.890611442640554f * x * y * z; break;
                case 11: v = -0.457045799464466f * y * (5.0f*z2 - 1.0f); break;
                case 12: v = 0.373176332590115f * z * (5.0f*z2 - 3.0f); break;
                case 13: v = -0.457045799464466f * x * (5.0f*z2 - 1.0f); break;
                default: v = (j == 14) ? 1.445305721320277f * z * (x2 - y2)
                                       : -0.590043589926644f * x * (x2 - 3.0f*y2); break;
            }
            ynms[sg][j] = v;
        }

        float excl = 0.0f, cm0 = 0.0f, cm1 = 0.0f, cm2 = 0.0f, am = 0.0f, dm = 0.0f;

        __syncthreads();   // ynms ready; also fences previous iteration's buffers

        for (int c = 0; c < T_SAMPLES / S_CHUNK; ++c) {
            // ---- layer 1: 3 -> 128 (per-thread hidden unit j, 8 samples) ----
            float h1v[S_CHUNK];
            unsigned ins = 0;
            #pragma unroll
            for (int s = 0; s < S_CHUNK; ++s) {
                const float t  = tn + ((float)(c*S_CHUNK + s) + 0.5f) * tstep;
                const float px = ox + dx*t, py = oy + dy*t, pz = oz + dz*t;
                const float nx = (px - a0x)*scx - 1.0f;
                const float ny = (py - a0y)*scy - 1.0f;
                const float nz = (pz - a0z)*scz - 1.0f;
                const bool inb = (nx >= -1.0f) & (nx <= 1.0f) & (ny >= -1.0f) & (ny <= 1.0f)
                               & (nz >= -1.0f) & (nz <= 1.0f);
                ins |= (inb ? 1u : 0u) << s;
                float h = b1s[j];
                h = fmaf(nx, W1s[0][j], h);
                h = fmaf(ny, W1s[1][j], h);
                h = fmaf(nz, W1s[2][j], h);
                h1v[s] = fmaxf(h, 0.0f);
            }
            *(float4*)&h1s[sg][j][0] = make_float4(h1v[0], h1v[1], h1v[2], h1v[3]);
            *(float4*)&h1s[sg][j][4] = make_float4(h1v[4], h1v[5], h1v[6], h1v[7]);
            __syncthreads();

            // ---- layer 2: 128 -> 128 (register-blocked over 8 samples) ----
            float acc[S_CHUNK];
            #pragma unroll
            for (int s = 0; s < S_CHUNK; ++s) acc[s] = b2s[j];
            #pragma unroll 4
            for (int k = 0; k < HID; ++k) {
                const float w = W2s[k][j];
                const float4 ha = *(const float4*)&h1s[sg][k][0];
                const float4 hb = *(const float4*)&h1s[sg][k][4];
                acc[0] = fmaf(ha.x, w, acc[0]);
                acc[1] = fmaf(ha.y, w, acc[1]);
                acc[2] = fmaf(ha.z, w, acc[2]);
                acc[3] = fmaf(ha.w, w, acc[3]);
                acc[4] = fmaf(hb.x, w, acc[4]);
                acc[5] = fmaf(hb.y, w, acc[5]);
                acc[6] = fmaf(hb.z, w, acc[6]);
                acc[7] = fmaf(hb.w, w, acc[7]);
            }
            #pragma unroll
            for (int s = 0; s < S_CHUNK; ++s) acc[s] = fmaxf(acc[s], 0.0f);
            *(float4*)&h2s[sg][j][0] = make_float4(acc[0], acc[1], acc[2], acc[3]);
            *(float4*)&h2s[sg][j][4] = make_float4(acc[4], acc[5], acc[6], acc[7]);
            __syncthreads();

            // ---- feat (16 outs) as 128 parallel tasks + sigma via k-sliced reduce ----
            {
                float fs = bfs[jf];
                #pragma unroll 8
                for (int k = 0; k < HID; ++k)
                    fs = fmaf(h2s[sg][k][sf], Wfs[k][jf], fs);
                cats[sg][sf][jf]      = fs;
                cats[sg][sf][16 + jf] = ynms[sg][jf];

                float ps = 0.0f;
                #pragma unroll
                for (int k = jf*8; k < jf*8 + 8; ++k)
                    ps = fmaf(h2s[sg][k][sf], Wds[k], ps);
                ps += __shfl_xor(ps, 1);
                ps += __shfl_xor(ps, 2);
                ps += __shfl_xor(ps, 4);
                ps += __shfl_xor(ps, 8);
                if (jf == 0)
                    sigs[sg][sf] = ((ins >> sf) & 1u) ? expf(ps + bds) : 0.0f;
            }
            __syncthreads();

            // ---- color layer 1: 32 -> 128 ----
            float hcv[S_CHUNK];
            #pragma unroll
            for (int s = 0; s < S_CHUNK; ++s) hcv[s] = bc1s[j];
            #pragma unroll
            for (int k4 = 0; k4 < 8; ++k4) {
                const float w0 = Wc1s[k4*4+0][j];
                const float w1 = Wc1s[k4*4+1][j];
                const float w2 = Wc1s[k4*4+2][j];
                const float w3 = Wc1s[k4*4+3][j];
                #pragma unroll
                for (int s = 0; s < S_CHUNK; ++s) {
                    const float4 cv = *(const float4*)&cats[sg][s][k4*4];
                    hcv[s] = fmaf(cv.x, w0, hcv[s]);
                    hcv[s] = fmaf(cv.y, w1, hcv[s]);
                    hcv[s] = fmaf(cv.z, w2, hcv[s]);
                    hcv[s] = fmaf(cv.w, w3, hcv[s]);
                }
            }
            #pragma unroll
            for (int s = 0; s < S_CHUNK; ++s) hcv[s] = fmaxf(hcv[s], 0.0f);
            // reuse h1s as hc buffer
            *(float4*)&h1s[sg][j][0] = make_float4(hcv[0], hcv[1], hcv[2], hcv[3]);
            *(float4*)&h1s[sg][j][4] = make_float4(hcv[4], hcv[5], hcv[6], hcv[7]);
            __syncthreads();

            // ---- color layer 2: 128 -> 3, k-sliced partials + butterfly ----
            {
                float p0 = 0.0f, p1 = 0.0f, p2 = 0.0f;
                #pragma unroll
                for (int k = jf*8; k < jf*8 + 8; ++k) {
                    const float hv = h1s[sg][k][sf];
                    p0 = fmaf(hv, Wc2s[k][0], p0);
                    p1 = fmaf(hv, Wc2s[k][1], p1);
                    p2 = fmaf(hv, Wc2s[k][2], p2);
                }
                p0 += __shfl_xor(p0, 1); p0 += __shfl_xor(p0, 2); p0 += __shfl_xor(p0, 4); p0 += __shfl_xor(p0, 8);
                p1 += __shfl_xor(p1, 1); p1 += __shfl_xor(p1, 2); p1 += __shfl_xor(p1, 4); p1 += __shfl_xor(p1, 8);
                p2 += __shfl_xor(p2, 1); p2 += __shfl_xor(p2, 2); p2 += __shfl_xor(p2, 4); p2 += __shfl_xor(p2, 8);
                if (jf == 0) {
                    cols[sg][sf][0] = 1.0f / (1.0f + expf(-(p0 + bc2s[0])));
                    cols[sg][sf][1] = 1.0f / (1.0f + expf(-(p1 + bc2s[1])));
                    cols[sg][sf][2] = 1.0f / (1.0f + expf(-(p2 + bc2s[2])));
                }
            }
            __syncthreads();

            // ---- integrate (redundant across sub-group lanes; sequential in s) ----
            #pragma unroll
            for (int s = 0; s < S_CHUNK; ++s) {
                const int sgl = c*S_CHUNK + s;
                const float sig = sigs[sg][s];
                const float delta = (sgl == T_SAMPLES-1)
                                  ? (tf + BOOSTER - (tn + ((float)T_SAMPLES - 0.5f) * tstep))
                                  : tstep;
                const float tau = sig * delta * dnorm;
                const float w = expf(-excl) * (1.0f - expf(-tau));
                excl += tau;
                const float t = tn + ((float)sgl + 0.5f) * tstep;
                cm0 = fmaf(w, cols[sg][s][0], cm0);
                cm1 = fmaf(w, cols[sg][s][1], cm1);
                cm2 = fmaf(w, cols[sg][s][2], cm2);
                am += w;
                dm = fmaf(w, t, dm);
            }
            // next chunk's first write (h1s) is fenced by the barrier after layer-1 store
        }

        if (j == 0) {
            const float amask = act ? 1.0f : 0.0f;
            out[ray*5 + 0] = cm0 * amask;
            out[ray*5 + 1] = cm1 * amask;
            out[ray*5 + 2] = cm2 * amask;
            out[ray*5 + 3] = am  * amask;
            out[ray*5 + 4] = dm  * amask;
        }
        __syncthreads();   // protect per-ray LDS before next g iteration
    }
}

extern "C" void kernel_launch(void* const* d_in, const int* in_sizes, int n_in,
                              void* d_out, int out_size, void* d_ws, size_t ws_size,
                              hipStream_t stream) {
    (void)in_sizes; (void)n_in; (void)d_ws; (void)ws_size; (void)out_size;
    const float* rays_o = (const float*)d_in[0];
    const float* rays_d = (const float*)d_in[1];
    const float* aabb   = (const float*)d_in[2];
    const float* W1  = (const float*)d_in[3];
    const float* b1  = (const float*)d_in[4];
    const float* W2  = (const float*)d_in[5];
    const float* b2  = (const float*)d_in[6];
    const float* Wd  = (const float*)d_in[7];
    const float* bd  = (const float*)d_in[8];
    const float* Wf  = (const float*)d_in[9];
    const float* bf  = (const float*)d_in[10];
    const float* Wc1 = (const float*)d_in[11];
    const float* bc1 = (const float*)d_in[12];
    const float* Wc2 = (const float*)d_in[13];
    const float* bc2 = (const float*)d_in[14];
    float* out = (float*)d_out;

    hipLaunchKernelGGL(RadianceRenderer_kernel, dim3(256), dim3(THREADS), 0, stream,
                       rays_o, rays_d, aabb, W1, b1, W2, b2, Wd, bd,
                       Wf, bf, Wc1, bc1, Wc2, bc2, out);
}

// Round 2
// 196.847 us; speedup vs baseline: 4.7919x; 4.7919x over previous
//
#include <hip/hip_runtime.h>
#include <math.h>

#define THREADS 256
#define NRAYS 8192
#define FAR_T 10.0f

typedef __attribute__((ext_vector_type(8))) short short8;
typedef __attribute__((ext_vector_type(4))) float f32x4;

static __device__ __forceinline__ unsigned f2bfu(float f) {
    unsigned u = __builtin_bit_cast(unsigned, f);
    return (u + 0x7fffu + ((u >> 16) & 1u)) >> 16;
}
static __device__ __forceinline__ unsigned pk2(float a, float b) {
    return f2bfu(a) | (f2bfu(b) << 16);
}
// swizzled short-index for [r][128] bf16 tiles (row stride 256B): XOR byte bits 4-6 by r&7
static __device__ __forceinline__ int sw128(int r, int k) {
    return (r << 7) + (k ^ ((r & 7) << 3));
}
// swizzled short-index for [r][32] bf16 tiles (row stride 64B)
static __device__ __forceinline__ int sw32(int r, int k) {
    return (r << 5) + (k ^ ((r & 3) << 3));
}
static __device__ __forceinline__ f32x4 MFMA16(short8 a, short8 b, f32x4 c) {
    return __builtin_amdgcn_mfma_f32_16x16x32_bf16(a, b, c, 0, 0, 0);
}

struct RayP { float ox,oy,oz,dx,dy,dz,tn,tf,tstep,dnorm; bool act; };

static __device__ __forceinline__ RayP raySetup(const float* __restrict__ ro, const float* __restrict__ rd,
        int r, float a0x,float a0y,float a0z,float a1x,float a1y,float a1z) {
    RayP R;
    R.ox=ro[3*r+0]; R.oy=ro[3*r+1]; R.oz=ro[3*r+2];
    R.dx=rd[3*r+0]; R.dy=rd[3*r+1]; R.dz=rd[3*r+2];
    float ivx=1.f/R.dx, ivy=1.f/R.dy, ivz=1.f/R.dz;
    float t1x=(a0x-R.ox)*ivx, t2x=(a1x-R.ox)*ivx;
    float t1y=(a0y-R.oy)*ivy, t2y=(a1y-R.oy)*ivy;
    float t1z=(a0z-R.oz)*ivz, t2z=(a1z-R.oz)*ivz;
    float tn = fmaxf(fmaxf(fminf(t1x,t2x),fminf(t1y,t2y)),fminf(t1z,t2z));
    tn = fmaxf(tn, 0.f);
    float tf = fminf(fminf(fmaxf(t1x,t2x),fmaxf(t1y,t2y)),fmaxf(t1z,t2z));
    tf = fminf(tf, FAR_T);
    R.act = tn < tf;
    R.tn = R.act ? tn : 0.f;
    R.tf = R.act ? tf : 1.f;
    R.tstep = (R.tf - R.tn) * (1.f/64.f);
    R.dnorm = sqrtf(R.dx*R.dx + R.dy*R.dy + R.dz*R.dz);
    return R;
}

__global__ __launch_bounds__(THREADS, 1)
void RadianceRenderer_kernel(const float* __restrict__ rays_o, const float* __restrict__ rays_d,
                             const float* __restrict__ aabb,
                             const float* __restrict__ W1, const float* __restrict__ b1,
                             const float* __restrict__ W2, const float* __restrict__ b2,
                             const float* __restrict__ Wd, const float* __restrict__ bd,
                             const float* __restrict__ Wf, const float* __restrict__ bf,
                             const float* __restrict__ Wc1, const float* __restrict__ bc1,
                             const float* __restrict__ Wc2, const float* __restrict__ bc2,
                             float* __restrict__ out)
{
    // weights stored transposed [out-ch][k] bf16 swizzled; activations [sample][k] bf16 swizzled
    __shared__ short W2T[128*128];   // 32 KB
    __shared__ short WfdT[32*128];   // 8 KB  rows 0-15=Wf cols, 16=Wd, 17-31=0
    __shared__ short Wc1T[128*32];   // 8 KB
    __shared__ short Wc2T[16*128];   // 4 KB  rows 0-2=Wc2 cols, rest 0
    __shared__ short H1[128*128];    // 32 KB (layer-1 out, reused as HC)
    __shared__ short H2[128*128];    // 32 KB
    __shared__ short CC[128*32];     // 8 KB  cols 0-15 feat, 16-31 ynm
    __shared__ float SIG[128];
    __shared__ float COL[128*4];

    const int tid  = threadIdx.x;
    const int lane = tid & 63;
    const int wv   = tid >> 6;        // wave 0..3
    const int l15  = lane & 15;
    const int l4   = lane >> 4;       // 0..3

    // ---- stage weights (one-time): transpose + bf16 + swizzle ----
    for (int i = tid; i < 128*128; i += THREADS) {
        int k = i >> 7, n = i & 127;
        W2T[sw128(n, k)] = (short)f2bfu(W2[i]);
    }
    for (int i = tid; i < 32*128; i += THREADS) {
        int n = i >> 7, k = i & 127;
        float v = (n < 16) ? Wf[k*16 + n] : ((n == 16) ? Wd[k] : 0.f);
        WfdT[sw128(n, k)] = (short)f2bfu(v);
    }
    for (int i = tid; i < 128*32; i += THREADS) {
        int n = i >> 5, k = i & 31;
        Wc1T[sw32(n, k)] = (short)f2bfu(Wc1[k*128 + n]);
    }
    for (int i = tid; i < 16*128; i += THREADS) {
        int c = i >> 7, k = i & 127;
        float v = (c < 3) ? Wc2[k*3 + c] : 0.f;
        Wc2T[sw128(c, k)] = (short)f2bfu(v);
    }
    __syncthreads();

    // ---- per-wave invariant register preloads ----
    const int chB = (wv >> 1) * 64;   // channel base (L2'/G4')
    const int smB = (wv & 1) * 64;    // sample base  (L2'/G4')
    const int sB3 = wv * 32;          // sample base  (G3'/G5')

    short8 w2f[4][4], wfdf[2][4], wc1f[4], wc2f[4];
    #pragma unroll
    for (int jn = 0; jn < 4; ++jn)
        #pragma unroll
        for (int kk = 0; kk < 4; ++kk)
            w2f[jn][kk] = *(const short8*)&W2T[sw128(chB + 16*jn + l15, kk*32 + 8*l4)];
    #pragma unroll
    for (int cg = 0; cg < 2; ++cg)
        #pragma unroll
        for (int kk = 0; kk < 4; ++kk)
            wfdf[cg][kk] = *(const short8*)&WfdT[sw128(16*cg + l15, kk*32 + 8*l4)];
    #pragma unroll
    for (int cg = 0; cg < 4; ++cg)
        wc1f[cg] = *(const short8*)&Wc1T[sw32(chB + 16*cg + l15, 8*l4)];
    #pragma unroll
    for (int kk = 0; kk < 4; ++kk)
        wc2f[kk] = *(const short8*)&Wc2T[sw128(l15, kk*32 + 8*l4)];

    float b2r[4][4], bc1r[4][4], bfr4[4], bc2r[3];
    #pragma unroll
    for (int jn = 0; jn < 4; ++jn)
        #pragma unroll
        for (int vv = 0; vv < 4; ++vv) {
            b2r[jn][vv]  = b2[chB + 16*jn + 4*l4 + vv];
            bc1r[jn][vv] = bc1[chB + 16*jn + 4*l4 + vv];
        }
    #pragma unroll
    for (int vv = 0; vv < 4; ++vv) bfr4[vv] = bf[4*l4 + vv];
    bc2r[0] = bc2[0]; bc2r[1] = bc2[1]; bc2r[2] = bc2[2];
    const float bdr = bd[0];

    // phase-A per-thread invariants: j-octet of W1/b1
    const int jo = tid & 15, mg = tid >> 4;
    float w1r[3][8], b1r[8];
    #pragma unroll
    for (int c = 0; c < 3; ++c)
        #pragma unroll
        for (int e = 0; e < 8; ++e) w1r[c][e] = W1[c*128 + jo*8 + e];
    #pragma unroll
    for (int e = 0; e < 8; ++e) b1r[e] = b1[jo*8 + e];

    const float a0x=aabb[0],a0y=aabb[1],a0z=aabb[2],a1x=aabb[3],a1y=aabb[4],a1z=aabb[5];
    const float scx=2.f/(a1x-a0x), scy=2.f/(a1y-a0y), scz=2.f/(a1z-a0z);

    for (int g = blockIdx.x; g < NRAYS/2; g += gridDim.x) {
        // ================= Phase A: layer-1 (VALU) + ynm fill =================
        {
            RayP R = raySetup(rays_o, rays_d, 2*g + (mg >> 3), a0x,a0y,a0z,a1x,a1y,a1z);
            #pragma unroll
            for (int e = 0; e < 8; ++e) {
                int m = mg*8 + e;
                int s = m & 63;
                float t  = R.tn + ((float)s + 0.5f) * R.tstep;
                float px = fmaf(R.dx, t, R.ox);
                float py = fmaf(R.dy, t, R.oy);
                float pz = fmaf(R.dz, t, R.oz);
                float nx = fmaf(px - a0x, scx, -1.f);
                float ny = fmaf(py - a0y, scy, -1.f);
                float nz = fmaf(pz - a0z, scz, -1.f);
                float h[8];
                #pragma unroll
                for (int jj = 0; jj < 8; ++jj) {
                    float v = fmaf(nx, w1r[0][jj], fmaf(ny, w1r[1][jj], fmaf(nz, w1r[2][jj], b1r[jj])));
                    h[jj] = fmaxf(v, 0.f);
                }
                uint4 q = make_uint4(pk2(h[0],h[1]), pk2(h[2],h[3]), pk2(h[4],h[5]), pk2(h[6],h[7]));
                *(uint4*)&H1[sw128(m, jo*8)] = q;
            }
            // ynm → CC[:,16:32]
            int m2 = tid >> 1, half = tid & 1;
            int rr = 2*g + (tid >> 7);
            float ddx = rays_d[3*rr+0], ddy = rays_d[3*rr+1], ddz = rays_d[3*rr+2];
            float inorm = rsqrtf(ddx*ddx + ddy*ddy + ddz*ddz);
            float x = ddx*inorm, y = ddy*inorm, z = ddz*inorm;
            float x2 = x*x, y2 = y*y, z2 = z*z;
            unsigned q0,q1,q2,q3;
            if (half == 0) {
                q0 = pk2(0.282094791773878f,            -0.488602511902920f*y);
                q1 = pk2(0.488602511902920f*z,          -0.488602511902920f*x);
                q2 = pk2(1.092548430592079f*x*y,        -1.092548430592079f*y*z);
                q3 = pk2(0.315391565252520f*(3.f*z2-1.f), -1.092548430592079f*x*z);
            } else {
                q0 = pk2(0.546274215296040f*(x2-y2),    -0.590043589926644f*y*(3.f*x2-y2));
                q1 = pk2(2.890611442640554f*x*y*z,      -0.457045799464466f*y*(5.f*z2-1.f));
                q2 = pk2(0.373176332590115f*z*(5.f*z2-3.f), -0.457045799464466f*x*(5.f*z2-1.f));
                q3 = pk2(1.445305721320277f*z*(x2-y2),  -0.590043589926644f*x*(x2-3.f*y2));
            }
            *(uint4*)&CC[sw32(m2, 16 + half*8)] = make_uint4(q0,q1,q2,q3);
        }
        __syncthreads();

        // ================= L2': H2 = relu(W2^T · H1^T) =================
        {
            f32x4 acc[4][4];
            #pragma unroll
            for (int jn = 0; jn < 4; ++jn)
                #pragma unroll
                for (int im = 0; im < 4; ++im) acc[jn][im] = (f32x4){0.f,0.f,0.f,0.f};
            #pragma unroll
            for (int kk = 0; kk < 4; ++kk) {
                short8 bfr[4];
                #pragma unroll
                for (int im = 0; im < 4; ++im)
                    bfr[im] = *(const short8*)&H1[sw128(smB + 16*im + l15, kk*32 + 8*l4)];
                #pragma unroll
                for (int jn = 0; jn < 4; ++jn)
                    #pragma unroll
                    for (int im = 0; im < 4; ++im)
                        acc[jn][im] = MFMA16(w2f[jn][kk], bfr[im], acc[jn][im]);
            }
            #pragma unroll
            for (int jn = 0; jn < 4; ++jn)
                #pragma unroll
                for (int im = 0; im < 4; ++im) {
                    int m  = smB + 16*im + l15;
                    int n0 = chB + 16*jn + 4*l4;
                    f32x4 v = acc[jn][im];
                    float r0 = fmaxf(v[0] + b2r[jn][0], 0.f);
                    float r1 = fmaxf(v[1] + b2r[jn][1], 0.f);
                    float r2 = fmaxf(v[2] + b2r[jn][2], 0.f);
                    float r3 = fmaxf(v[3] + b2r[jn][3], 0.f);
                    *(uint2*)&H2[sw128(m, n0)] = make_uint2(pk2(r0,r1), pk2(r2,r3));
                }
        }
        __syncthreads();

        // ================= G3': feat(+bf) → CC[:,0:16], sigma-dot → SIG =================
        {
            f32x4 f3[2][2];
            #pragma unroll
            for (int cg = 0; cg < 2; ++cg) { f3[cg][0] = (f32x4){0,0,0,0}; f3[cg][1] = (f32x4){0,0,0,0}; }
            #pragma unroll
            for (int kk = 0; kk < 4; ++kk) {
                short8 bA = *(const short8*)&H2[sw128(sB3 +      l15, kk*32 + 8*l4)];
                short8 bB = *(const short8*)&H2[sw128(sB3 + 16 + l15, kk*32 + 8*l4)];
                #pragma unroll
                for (int cg = 0; cg < 2; ++cg) {
                    f3[cg][0] = MFMA16(wfdf[cg][kk], bA, f3[cg][0]);
                    f3[cg][1] = MFMA16(wfdf[cg][kk], bB, f3[cg][1]);
                }
            }
            #pragma unroll
            for (int sg = 0; sg < 2; ++sg) {
                int m = sB3 + 16*sg + l15;
                f32x4 v = f3[0][sg];
                *(uint2*)&CC[sw32(m, 4*l4)] =
                    make_uint2(pk2(v[0]+bfr4[0], v[1]+bfr4[1]), pk2(v[2]+bfr4[2], v[3]+bfr4[3]));
                if (l4 == 0) SIG[m] = f3[1][sg][0];   // row 16 = Wd dot (bias added later)
            }
        }
        __syncthreads();

        // ================= G4': HC = relu(Wc1^T · CC^T) → H1 buffer =================
        {
            f32x4 g4[4][4];
            #pragma unroll
            for (int cg = 0; cg < 4; ++cg)
                #pragma unroll
                for (int sg = 0; sg < 4; ++sg) g4[cg][sg] = (f32x4){0,0,0,0};
            short8 bcc[4];
            #pragma unroll
            for (int sg = 0; sg < 4; ++sg)
                bcc[sg] = *(const short8*)&CC[sw32(smB + 16*sg + l15, 8*l4)];
            #pragma unroll
            for (int cg = 0; cg < 4; ++cg)
                #pragma unroll
                for (int sg = 0; sg < 4; ++sg)
                    g4[cg][sg] = MFMA16(wc1f[cg], bcc[sg], g4[cg][sg]);
            #pragma unroll
            for (int cg = 0; cg < 4; ++cg)
                #pragma unroll
                for (int sg = 0; sg < 4; ++sg) {
                    int m  = smB + 16*sg + l15;
                    int n0 = chB + 16*cg + 4*l4;
                    f32x4 v = g4[cg][sg];
                    float r0 = fmaxf(v[0] + bc1r[cg][0], 0.f);
                    float r1 = fmaxf(v[1] + bc1r[cg][1], 0.f);
                    float r2 = fmaxf(v[2] + bc1r[cg][2], 0.f);
                    float r3 = fmaxf(v[3] + bc1r[cg][3], 0.f);
                    *(uint2*)&H1[sw128(m, n0)] = make_uint2(pk2(r0,r1), pk2(r2,r3));
                }
        }
        __syncthreads();

        // ================= G5': color = sigmoid(Wc2^T · HC^T + bc2) =================
        {
            f32x4 c5[2] = { (f32x4){0,0,0,0}, (f32x4){0,0,0,0} };
            #pragma unroll
            for (int kk = 0; kk < 4; ++kk) {
                #pragma unroll
                for (int sg = 0; sg < 2; ++sg) {
                    short8 b = *(const short8*)&H1[sw128(sB3 + 16*sg + l15, kk*32 + 8*l4)];
                    c5[sg] = MFMA16(wc2f[kk], b, c5[sg]);
                }
            }
            if (l4 == 0) {
                #pragma unroll
                for (int sg = 0; sg < 2; ++sg) {
                    int m = sB3 + 16*sg + l15;
                    #pragma unroll
                    for (int vv = 0; vv < 3; ++vv)
                        COL[m*4 + vv] = 1.f / (1.f + expf(-(c5[sg][vv] + bc2r[vv])));
                }
            }
        }
        __syncthreads();

        // ================= Phase F: transmittance integration (waves 0,1) =================
        if (wv < 2) {
            RayP R = raySetup(rays_o, rays_d, 2*g + wv, a0x,a0y,a0z,a1x,a1y,a1z);
            int m = wv*64 + lane;
            float t  = R.tn + ((float)lane + 0.5f) * R.tstep;
            float px = fmaf(R.dx, t, R.ox);
            float py = fmaf(R.dy, t, R.oy);
            float pz = fmaf(R.dz, t, R.oz);
            float nx = fmaf(px - a0x, scx, -1.f);
            float ny = fmaf(py - a0y, scy, -1.f);
            float nz = fmaf(pz - a0z, scz, -1.f);
            bool ins = (nx >= -1.f) & (nx <= 1.f) & (ny >= -1.f) & (ny <= 1.f)
                     & (nz >= -1.f) & (nz <= 1.f);
            float sig = ins ? expf(SIG[m] + bdr) : 0.f;
            float delta = (lane == 63) ? (R.tf + 1.0f - t) : R.tstep;
            float tau = sig * delta * R.dnorm;
            // exclusive prefix sum over 64 lanes
            float cum = tau;
            #pragma unroll
            for (int off = 1; off < 64; off <<= 1) {
                float tmp = __shfl_up(cum, off);
                if (lane >= off) cum += tmp;
            }
            float excl = cum - tau;
            float wgt = expf(-excl) * (1.f - expf(-tau));
            float c0 = wgt * COL[m*4+0];
            float c1 = wgt * COL[m*4+1];
            float c2 = wgt * COL[m*4+2];
            float amv = wgt;
            float dmv = wgt * t;
            #pragma unroll
            for (int off = 32; off; off >>= 1) {
                c0  += __shfl_xor(c0,  off);
                c1  += __shfl_xor(c1,  off);
                c2  += __shfl_xor(c2,  off);
                amv += __shfl_xor(amv, off);
                dmv += __shfl_xor(dmv, off);
            }
            if (lane == 0) {
                float msk = R.act ? 1.f : 0.f;
                int ray = 2*g + wv;
                out[ray*5+0] = c0*msk;
                out[ray*5+1] = c1*msk;
                out[ray*5+2] = c2*msk;
                out[ray*5+3] = amv*msk;
                out[ray*5+4] = dmv*msk;
            }
        }
        __syncthreads();
    }
}

extern "C" void kernel_launch(void* const* d_in, const int* in_sizes, int n_in,
                              void* d_out, int out_size, void* d_ws, size_t ws_size,
                              hipStream_t stream) {
    (void)in_sizes; (void)n_in; (void)d_ws; (void)ws_size; (void)out_size;
    const float* rays_o = (const float*)d_in[0];
    const float* rays_d = (const float*)d_in[1];
    const float* aabb   = (const float*)d_in[2];
    const float* W1  = (const float*)d_in[3];
    const float* b1  = (const float*)d_in[4];
    const float* W2  = (const float*)d_in[5];
    const float* b2  = (const float*)d_in[6];
    const float* Wd  = (const float*)d_in[7];
    const float* bd  = (const float*)d_in[8];
    const float* Wf  = (const float*)d_in[9];
    const float* bf  = (const float*)d_in[10];
    const float* Wc1 = (const float*)d_in[11];
    const float* bc1 = (const float*)d_in[12];
    const float* Wc2 = (const float*)d_in[13];
    const float* bc2 = (const float*)d_in[14];
    float* out = (float*)d_out;

    hipLaunchKernelGGL(RadianceRenderer_kernel, dim3(256), dim3(THREADS), 0, stream,
                       rays_o, rays_d, aabb, W1, b1, W2, b2, Wd, bd,
                       Wf, bf, Wc1, bc1, Wc2, bc2, out);
}